// Round 1
// baseline (507.860 us; speedup 1.0000x reference)
//
#include <hip/hip_runtime.h>

// CrossEntropyLoss_37254546326109 — fused CE + VAR + Inter + Center loss.
// logit [8,21,512,512] f32, target [8,1,512,512] i32, features [8,262144,32] f32.
// loss = (CE + 1.0*VAR + 0.5*Inter + 0.1*Center)/8, scalar f32 output.
//
// R1 lesson: fp32 atomics compile to CAS loops — zero fp32 atomics anywhere.
// R2 theory: both heavy kernels sat at ~115-120 live VGPRs under the 128-reg
// cap from __launch_bounds__(256,4) -> suspected scratch spills in the hot
// loops. This version (a) stages logit channels in chunks of 7 (28 regs in
// flight instead of 84), (b) fuses pixel+feature work into ONE dispatch so
// the dominant kernel is visible in rocprof top-5 next round, (c) keeps the
// register-heavy feature loop as the sole peak (~105 regs < 128 cap).

constexpr int   N_IMG  = 8;
constexpr int   C_CLS  = 21;
constexpr int   P_PIX  = 512 * 512;     // pixels per image
constexpr int   PQ     = P_PIX / 4;     // float4-quads per image per channel
constexpr int   IGN    = 255;
constexpr float ALPHA  = 1.0f, BETA = 0.5f, GAMMA = 0.1f;

constexpr int MAIN_BLOCKS = 1024;   // 128 per image, 2048 px each (both phases)
constexpr int FEAT_ITERS  = 64;     // 32 px per iteration per block

// Workspace layout (4-byte units). Total ~2.9 MB.
constexpr int OFF_PIX  = 0;                               // [1024][4] f32
constexpr int OFF_SSQ  = OFF_PIX + MAIN_BLOCKS * 4;       // [1024]    f32
constexpr int OFF_CLS  = OFF_SSQ + MAIN_BLOCKS;           // [1024][672] f32
constexpr int OFF_CNT  = OFF_CLS + MAIN_BLOCKS * 672;     // [1024][21] i32
constexpr int OFF_MEAN = OFF_CNT + MAIN_BLOCKS * C_CLS;   // [168] f32

// ---------------------------------------------------------------------------
// Kernel 1 (fused): per-pixel logit terms + label histogram + center-loss
// class sums. One block = one (img, 2048-pixel chunk).
//
// Phase A (logits): thread = 4 pixels (float4 across pixels, channel stride
// PQ -> coalesced). 2 sequential quad-iterations. Channels staged in chunks
// of 7 so only 28 load-regs are live (vs 84 before) — no spill pressure,
// still 7 outstanding 1KB wave-loads for MLP.
//
// Phase B (features): 256 threads = 32 pixel-lanes x 8 dim-groups; thread
// holds float4 acc[21]; masked FMA per class; loads software-pipelined one
// iteration ahead. Register accumulators, no atomics.
// ---------------------------------------------------------------------------
__global__ __launch_bounds__(256, 4) void main_kernel(
    const float* __restrict__ logit, const int* __restrict__ target,
    const float* __restrict__ feats, float* __restrict__ ws)
{
    __shared__ int    s_hist[C_CLS];
    __shared__ float  s_red[4][4];
    __shared__ float4 s_part[4][8][C_CLS];   // [wave][dimgroup][class]
    __shared__ float  s_ssq[4];

    const int tid   = threadIdx.x;
    const int img   = blockIdx.x >> 7;       // 128 blocks per image
    const int chunk = blockIdx.x & 127;

    // ---------------- Phase A: logit terms + histogram --------------------
    if (tid < C_CLS) s_hist[tid] = 0;
    __syncthreads();

    float ce = 0.f, vm = 0.f, var = 0.f, inter = 0.f;

#pragma unroll 1
    for (int qi = 0; qi < 2; ++qi) {
        const int pq = chunk * 512 + qi * 256 + tid;          // quad index
        const int4 t = ((const int4*)target)[(size_t)img * PQ + pq];
        const float4* lp = (const float4*)logit + (size_t)img * C_CLS * PQ + pq;

        float4 s  = {0.f, 0.f, 0.f, 0.f};
        float4 sc = {0.f, 0.f, 0.f, 0.f};
        float4 lg = {0.f, 0.f, 0.f, 0.f};

#pragma unroll 1
        for (int cb = 0; cb < C_CLS; cb += 7) {
            float4 x[7];
#pragma unroll
            for (int i = 0; i < 7; ++i) x[i] = lp[(size_t)(cb + i) * PQ];
#pragma unroll
            for (int i = 0; i < 7; ++i) {
                const int ch = cb + i;
                const float4 v = x[i];
                s.x += __expf(v.x); s.y += __expf(v.y);
                s.z += __expf(v.z); s.w += __expf(v.w);
                sc.x += v.x; sc.y += v.y; sc.z += v.z; sc.w += v.w;
                lg.x = (t.x == ch) ? v.x : lg.x;
                lg.y = (t.y == ch) ? v.y : lg.y;
                lg.z = (t.z == ch) ? v.z : lg.z;
                lg.w = (t.w == ch) ? v.w : lg.w;
            }
        }

        // label histogram (int LDS atomics are native ds_add_u32)
        if (t.x != IGN) atomicAdd(&s_hist[t.x], 1);
        if (t.y != IGN) atomicAdd(&s_hist[t.y], 1);
        if (t.z != IGN) atomicAdd(&s_hist[t.z], 1);
        if (t.w != IGN) atomicAdd(&s_hist[t.w], 1);

        {
            const float v = (t.x != IGN) ? 1.f : 0.f;
            vm += v; ce += v * (__logf(s.x) - lg.x); var -= v * lg.x; inter += v * (sc.x - lg.x);
        }
        {
            const float v = (t.y != IGN) ? 1.f : 0.f;
            vm += v; ce += v * (__logf(s.y) - lg.y); var -= v * lg.y; inter += v * (sc.y - lg.y);
        }
        {
            const float v = (t.z != IGN) ? 1.f : 0.f;
            vm += v; ce += v * (__logf(s.z) - lg.z); var -= v * lg.z; inter += v * (sc.z - lg.z);
        }
        {
            const float v = (t.w != IGN) ? 1.f : 0.f;
            vm += v; ce += v * (__logf(s.w) - lg.w); var -= v * lg.w; inter += v * (sc.w - lg.w);
        }
    }

    for (int off = 32; off; off >>= 1) {
        ce    += __shfl_xor(ce, off);
        vm    += __shfl_xor(vm, off);
        var   += __shfl_xor(var, off);
        inter += __shfl_xor(inter, off);
    }
    const int wv = tid >> 6;
    if ((tid & 63) == 0) {
        s_red[wv][0] = ce; s_red[wv][1] = vm; s_red[wv][2] = var; s_red[wv][3] = inter;
    }
    __syncthreads();   // also orders the histogram atomics

    if (tid < 4) {
        ws[OFF_PIX + blockIdx.x * 4 + tid] =
            s_red[0][tid] + s_red[1][tid] + s_red[2][tid] + s_red[3][tid];
    }
    if (tid < C_CLS) {
        ((int*)ws)[OFF_CNT + blockIdx.x * C_CLS + tid] = s_hist[tid];
    }

    // ---------------- Phase B: center-loss class sums ---------------------
    const int p0 = chunk * 2048;
    const int pl = tid >> 3;              // pixel lane 0..31
    const int dg = tid & 7;               // dim group 0..7

    const float4* fb = (const float4*)feats + ((size_t)img * P_PIX + p0) * 8;
    const int*    tb = target + (size_t)img * P_PIX + p0;

    float4 acc[C_CLS];
#pragma unroll
    for (int c = 0; c < C_CLS; ++c) acc[c] = {0.f, 0.f, 0.f, 0.f};
    float ssq = 0.f;

    int    lab = tb[pl];
    float4 f   = fb[(size_t)pl * 8 + dg];
    for (int it = 0; it < FEAT_ITERS; ++it) {
        int    nlab = 0;
        float4 nf   = {0.f, 0.f, 0.f, 0.f};
        if (it + 1 < FEAT_ITERS) {
            nlab = tb[(it + 1) * 32 + pl];
            nf   = fb[(size_t)((it + 1) * 32 + pl) * 8 + dg];
        }
        const float vld = (lab != IGN) ? 1.f : 0.f;
        ssq += vld * (f.x * f.x + f.y * f.y + f.z * f.z + f.w * f.w);
#pragma unroll
        for (int c = 0; c < C_CLS; ++c) {
            const float m = (lab == c) ? 1.f : 0.f;
            acc[c].x += m * f.x; acc[c].y += m * f.y;
            acc[c].z += m * f.z; acc[c].w += m * f.w;
        }
        lab = nlab; f = nf;
    }

    // reduce across the 8 pixel-lanes sharing this dim-group within the wave
#pragma unroll
    for (int c = 0; c < C_CLS; ++c) {
        for (int off = 8; off <= 32; off <<= 1) {
            acc[c].x += __shfl_xor(acc[c].x, off);
            acc[c].y += __shfl_xor(acc[c].y, off);
            acc[c].z += __shfl_xor(acc[c].z, off);
            acc[c].w += __shfl_xor(acc[c].w, off);
        }
    }
    if ((tid & 63) < 8) {
#pragma unroll
        for (int c = 0; c < C_CLS; ++c) s_part[wv][dg][c] = acc[c];
    }

    for (int off = 1; off < 64; off <<= 1) ssq += __shfl_xor(ssq, off);
    if ((tid & 63) == 0) s_ssq[wv] = ssq;
    __syncthreads();

    if (tid < C_CLS * 8) {             // 168 threads: one float4 each
        const int c = tid >> 3, g = tid & 7;
        const float4 a = s_part[0][g][c], b = s_part[1][g][c];
        const float4 d = s_part[2][g][c], e = s_part[3][g][c];
        float4 v;
        v.x = a.x + b.x + d.x + e.x;
        v.y = a.y + b.y + d.y + e.y;
        v.z = a.z + b.z + d.z + e.z;
        v.w = a.w + b.w + d.w + e.w;
        // float offset: blk*672 + c*32 + g*4  (matches reduce_kernel)
        ((float4*)(ws + OFF_CLS))[(size_t)blockIdx.x * 168 + tid] = v;
    }
    if (tid == 0)
        ws[OFF_SSQ + blockIdx.x] = s_ssq[0] + s_ssq[1] + s_ssq[2] + s_ssq[3];
}

// ---------------------------------------------------------------------------
// Kernel 2: fold class-sum partials + count partials into 168 mean-terms.
// One block per (img, class). 128 threads.
// ---------------------------------------------------------------------------
__global__ __launch_bounds__(128) void reduce_kernel(float* __restrict__ ws)
{
    __shared__ float sred[128];
    __shared__ int   s_cnt;

    const int img = blockIdx.x / C_CLS;
    const int c   = blockIdx.x % C_CLS;
    const int tid = threadIdx.x;
    const int d   = tid & 31;         // dim
    const int qq  = tid >> 5;         // 0..3

    if (tid == 0) s_cnt = 0;
    __syncthreads();

    // counts: sum this image's 128 block histograms (one per thread)
    {
        const int* cp = (const int*)ws + OFF_CNT;
        const int cnt = cp[(img * 128 + tid) * C_CLS + c];
        atomicAdd(&s_cnt, cnt);
    }

    // class sums: sum this image's 128 block partials for (c, d)
    float s = 0.f;
    for (int b = qq; b < 128; b += 4)
        s += ws[OFF_CLS + (size_t)(img * 128 + b) * 672 + c * 32 + d];
    sred[tid] = s;
    __syncthreads();                  // also orders s_cnt atomics
    if (tid < 64) sred[tid] += sred[tid + 64];
    __syncthreads();
    if (tid < 32) {
        const float Sd = sred[tid] + sred[tid + 32];
        float n2 = Sd * Sd;
        for (int off = 1; off < 32; off <<= 1) n2 += __shfl_xor(n2, off);
        if (tid == 0)
            ws[OFF_MEAN + blockIdx.x] = n2 / fmaxf((float)s_cnt, 1.f);
    }
}

// ---------------------------------------------------------------------------
// Kernel 3: final combine.
// ---------------------------------------------------------------------------
__global__ __launch_bounds__(256) void finalize_kernel(
    const float* __restrict__ ws, float* __restrict__ out)
{
    __shared__ float fr[4][6];
    const int tid = threadIdx.x;

    float ce = 0.f, vm = 0.f, var = 0.f, inter = 0.f, ssq = 0.f, mean = 0.f;
    for (int b = tid; b < MAIN_BLOCKS; b += 256) {
        const float* p = ws + OFF_PIX + b * 4;
        ce += p[0]; vm += p[1]; var += p[2]; inter += p[3];
        ssq += ws[OFF_SSQ + b];
    }
    if (tid < N_IMG * C_CLS) mean = ws[OFF_MEAN + tid];

    for (int off = 32; off; off >>= 1) {
        ce   += __shfl_xor(ce, off);   vm    += __shfl_xor(vm, off);
        var  += __shfl_xor(var, off);  inter += __shfl_xor(inter, off);
        ssq  += __shfl_xor(ssq, off);  mean  += __shfl_xor(mean, off);
    }
    const int wv = tid >> 6;
    if ((tid & 63) == 0) {
        fr[wv][0] = ce;  fr[wv][1] = vm;   fr[wv][2] = var;
        fr[wv][3] = inter; fr[wv][4] = ssq; fr[wv][5] = mean;
    }
    __syncthreads();
    if (tid == 0) {
        const float CE_s  = fr[0][0] + fr[1][0] + fr[2][0] + fr[3][0];
        const float VM    = fr[0][1] + fr[1][1] + fr[2][1] + fr[3][1];
        const float VAR_s = fr[0][2] + fr[1][2] + fr[2][2] + fr[3][2];
        const float INT_s = fr[0][3] + fr[1][3] + fr[2][3] + fr[3][3];
        const float SSQ   = fr[0][4] + fr[1][4] + fr[2][4] + fr[3][4];
        const float MEAN  = fr[0][5] + fr[1][5] + fr[2][5] + fr[3][5];
        const float invP   = 1.f / (float)P_PIX;
        const float CE     = CE_s / fmaxf(VM, 1.f);
        const float VAR    = VAR_s * invP;
        const float Inter  = INT_s * invP;
        const float Center = (SSQ - MEAN) * invP;
        out[0] = (CE + ALPHA * VAR + BETA * Inter + GAMMA * Center) / (float)N_IMG;
    }
}

extern "C" void kernel_launch(void* const* d_in, const int* in_sizes, int n_in,
                              void* d_out, int out_size, void* d_ws, size_t ws_size,
                              hipStream_t stream)
{
    const float* logit  = (const float*)d_in[0];
    const int*   target = (const int*)d_in[1];
    const float* feats  = (const float*)d_in[2];
    float* ws  = (float*)d_ws;
    float* out = (float*)d_out;

    // No memset needed: every ws word consumed is written earlier in-stream.
    main_kernel    <<<MAIN_BLOCKS, 256, 0, stream>>>(logit, target, feats, ws);
    reduce_kernel  <<<N_IMG * C_CLS, 128, 0, stream>>>(ws);
    finalize_kernel<<<1, 256, 0, stream>>>(ws, out);
}